// Round 5
// baseline (171.081 us; speedup 1.0000x reference)
//
#include <hip/hip_runtime.h>

#define N 8192
#define M 4
#define L 256
#define THREADS 256

// ws layout (float offsets)
#define WS_E    0                 // [5][N]  exp(hazards), stream-major
#define WS_TC   (5 * N)           // [N]     compact times
#define WS_SE   (6 * N)           // [5][N]  rank-scattered e (zeroed in k1)
#define WS_SUF  (11 * N)          // [5][N]  suffix sums
#define WS_RANK (16 * N)          // [N]     ranks (stored as int)
#define WS_KM   (17 * N)          // [2560]  KL partials: [0,2048)=modality, [2048,2560)=joint

#define K1_TBL 48                 // 48*256 = 12288 = 10240 (E+zero) + 2048 (tc)
#define K1_KL  1024               // modality first half  (32 MB)
#define K2_RNK 256                // 256 blocks * 32 elements = 8192 ranks
#define K2_KL  1024               // modality second half (32 MB)
#define K3_SCN 5                  // one scan block per stream
#define K3_KL  512                // joint (16 MB)

__device__ __forceinline__ float waveSum(float v) {
#pragma unroll
    for (int off = 32; off > 0; off >>= 1) v += __shfl_down(v, off, 64);
    return v;
}

__device__ __forceinline__ float4 exp4(float4 h) {
    return make_float4(__expf(h.x), __expf(h.y), __expf(h.z), __expf(h.w));
}

__device__ __forceinline__ float kl4(float4 l, float4 s) {
    float k;
    k  = 0.5f * (s.x * s.x + l.x * l.x) - __logf(s.x) - 0.5f;
    k += 0.5f * (s.y * s.y + l.y * l.y) - __logf(s.y) - 0.5f;
    k += 0.5f * (s.z * s.z + l.z * l.z) - __logf(s.z) - 0.5f;
    k += 0.5f * (s.w * s.w + l.w * l.w) - __logf(s.w) - 0.5f;
    return k;
}

// ---- k1: E table + tc + zero sortedE  ∥  KL modality first half ----
__global__ __launch_bounds__(THREADS) void k1_prep(
    const float* __restrict__ jlh, const float* __restrict__ mlh,
    const float4* __restrict__ mloc4, const float4* __restrict__ mscale4,
    const float* __restrict__ target, float* __restrict__ ws)
{
    const int tid = threadIdx.x, bid = blockIdx.x;
    if (bid < K1_TBL) {
        const int idx = bid * THREADS + tid;                 // [0, 12288)
        if (idx < 10240) {
            const int s = idx >> 11, q = idx & 2047;         // 2048 f4 per stream
            const float4 h = (s == 0) ? ((const float4*)jlh)[q]
                                      : ((const float4*)mlh)[(s - 1) * 2048 + q];
            ((float4*)(ws + WS_E))[idx] = exp4(h);
            ((float4*)(ws + WS_SE))[idx] = make_float4(0.f, 0.f, 0.f, 0.f);
        } else {
            const int q = idx - 10240;                       // [0, 2048)
            const float4* tg4 = (const float4*)target;
            const float4 f1 = tg4[2 * q], f2 = tg4[2 * q + 1];
            ((float4*)(ws + WS_TC))[q] = make_float4(f1.x, f1.z, f2.x, f2.z);
        }
    } else {
        const int kb = bid - K1_TBL;                         // 0..1023
        float km = 0.f;
#pragma unroll
        for (int it = 0; it < 4; ++it) {
            const int idx = kb * 1024 + it * 256 + tid;      // [0, 1048576)
            km += kl4(mloc4[idx], mscale4[idx]);
        }
        km = waveSum(km);
        __shared__ float red[4];
        if ((tid & 63) == 0) red[tid >> 6] = km;
        __syncthreads();
        if (tid == 0) ws[WS_KM + kb] = red[0] + red[1] + red[2] + red[3];
    }
}

// ---- k2: ranks + scatter e into sorted slots  ∥  KL modality second half ----
__global__ __launch_bounds__(THREADS) void k2_rank(
    const float4* __restrict__ mloc4, const float4* __restrict__ mscale4,
    float* __restrict__ ws)
{
    const int tid = threadIdx.x, bid = blockIdx.x;
    if (bid < K2_RNK) {
        // 8 threads per element: sub s scans f4 indices s, s+8, s+16, ... (coalesced)
        const int e = bid * 32 + (tid >> 3);
        const int sub = tid & 7;
        const float ti = ws[WS_TC + e];
        const float4* __restrict__ tc4 = (const float4*)(ws + WS_TC);
        int r = 0;
#pragma unroll 4
        for (int k = 0; k < 256; ++k) {
            const float4 t4 = tc4[sub + 8 * k];
            r += (t4.x < ti) ? 1 : 0;
            r += (t4.y < ti) ? 1 : 0;
            r += (t4.z < ti) ? 1 : 0;
            r += (t4.w < ti) ? 1 : 0;
        }
        r += __shfl_xor(r, 1, 64);
        r += __shfl_xor(r, 2, 64);
        r += __shfl_xor(r, 4, 64);
        if (sub == 0) {
            ((int*)ws)[WS_RANK + e] = r;
#pragma unroll
            for (int s = 0; s < 5; ++s)
                atomicAdd(&ws[WS_SE + s * N + r], ws[WS_E + s * N + e]);
        }
    } else {
        const int kb = bid - K2_RNK;                         // 0..1023
        float km = 0.f;
#pragma unroll
        for (int it = 0; it < 4; ++it) {
            const int idx = 1048576 + kb * 1024 + it * 256 + tid;
            km += kl4(mloc4[idx], mscale4[idx]);
        }
        km = waveSum(km);
        __shared__ float red[4];
        if ((tid & 63) == 0) red[tid >> 6] = km;
        __syncthreads();
        if (tid == 0) ws[WS_KM + 1024 + kb] = red[0] + red[1] + red[2] + red[3];
    }
}

// ---- k3: suffix scan per stream (5 blocks)  ∥  KL joint ----
__global__ __launch_bounds__(THREADS) void k3_scan(
    const float4* __restrict__ jloc4, const float4* __restrict__ jscale4,
    float* __restrict__ ws)
{
    const int tid = threadIdx.x, bid = blockIdx.x;
    if (bid < K3_SCN) {
        const int s = bid;
        const float* __restrict__ src = ws + WS_SE + s * N;
        float* __restrict__ dst = ws + WS_SUF + s * N;
        float v[32];
#pragma unroll
        for (int k = 0; k < 8; ++k) {
            const float4 t = ((const float4*)src)[tid * 8 + k];
            v[4 * k] = t.x; v[4 * k + 1] = t.y; v[4 * k + 2] = t.z; v[4 * k + 3] = t.w;
        }
#pragma unroll
        for (int k = 30; k >= 0; --k) v[k] += v[k + 1];      // local inclusive suffix
        const float T = v[0];
        // inclusive wave-level suffix of per-thread totals
        float x = T;
        const int lane = tid & 63, w = tid >> 6;
#pragma unroll
        for (int off = 1; off < 64; off <<= 1) {
            const float y = __shfl_down(x, off, 64);
            if (lane + off < 64) x += y;
        }
        __shared__ float wt[4];
        if (lane == 0) wt[w] = x;                            // wave total
        __syncthreads();
        float off_w = 0.f;
        for (int ww = w + 1; ww < 4; ++ww) off_w += wt[ww];
        const float excl = off_w + (x - T);                  // strictly-later threads
#pragma unroll
        for (int k = 0; k < 8; ++k) {
            float4 o;
            o.x = excl + v[4 * k];
            o.y = excl + v[4 * k + 1];
            o.z = excl + v[4 * k + 2];
            o.w = excl + v[4 * k + 3];
            ((float4*)dst)[tid * 8 + k] = o;
        }
    } else {
        const int kb = bid - K3_SCN;                         // 0..511
        float kj = 0.f;
#pragma unroll
        for (int it = 0; it < 4; ++it) {
            const int idx = kb * 1024 + it * 256 + tid;      // [0, 524288)
            kj += kl4(jloc4[idx], jscale4[idx]);
        }
        kj = waveSum(kj);
        __shared__ float red[4];
        if ((tid & 63) == 0) red[tid >> 6] = kj;
        __syncthreads();
        if (tid == 0) ws[WS_KM + 2048 + kb] = red[0] + red[1] + red[2] + red[3];
    }
}

// ---- k4: gather risks + cox epilogue + combine everything ----
__global__ __launch_bounds__(1024) void k4_final(
    const float* __restrict__ jlh, const float* __restrict__ mlh,
    const float* __restrict__ target, const float* __restrict__ alpha_p,
    const float* __restrict__ beta_p, float* __restrict__ ws,
    float* __restrict__ out)
{
    const int tid = threadIdx.x;
    float c[5] = {0.f, 0.f, 0.f, 0.f, 0.f};
    float evs = 0.f;
#pragma unroll
    for (int k = 0; k < 8; ++k) {
        const int i = k * 1024 + tid;
        const float ev = target[2 * i + 1];
        evs += ev;
        const int r = ((const int*)ws)[WS_RANK + i];
#pragma unroll
        for (int s = 0; s < 5; ++s) {
            const float risk = ws[WS_SUF + s * N + r];
            const float h = (s == 0) ? jlh[i] : mlh[(s - 1) * N + i];
            c[s] += ev * (h - __logf(risk));
        }
    }
    float klm = 0.f, klj = 0.f;
    klm += ws[WS_KM + tid];
    klm += ws[WS_KM + 1024 + tid];
    if (tid < 512) klj = ws[WS_KM + 2048 + tid];

    // reduce 8 values across 16 waves
    float vals[8] = {c[0], c[1], c[2], c[3], c[4], evs, klm, klj};
    __shared__ float red[16][8];
    const int lane = tid & 63, w = tid >> 6;
#pragma unroll
    for (int q = 0; q < 8; ++q) {
        vals[q] = waveSum(vals[q]);
        if (lane == 0) red[w][q] = vals[q];
    }
    __syncthreads();
    if (tid == 0) {
        float t[8];
#pragma unroll
        for (int q = 0; q < 8; ++q) {
            float x = 0.f;
#pragma unroll
            for (int ww = 0; ww < 16; ++ww) x += red[ww][q];
            t[q] = x;
        }
        const float EV = t[5];
        const float alpha = alpha_p[0], beta = beta_p[0];
        const float cox_j = -t[0] / EV;
        const float cox_m = -(t[1] + t[2] + t[3] + t[4]) / EV;
        out[0] = cox_j + beta * (t[7] / (float)N) + alpha * (cox_m + beta * (t[6] / (float)N));
    }
}

extern "C" void kernel_launch(void* const* d_in, const int* in_sizes, int n_in,
                              void* d_out, int out_size, void* d_ws, size_t ws_size,
                              hipStream_t stream) {
    const float* jlh    = (const float*)d_in[0];  // (N,)
    const float* mlh    = (const float*)d_in[1];  // (M,N)
    const float* jloc   = (const float*)d_in[2];  // (N,L)
    const float* jscale = (const float*)d_in[3];  // (N,L)
    const float* mloc   = (const float*)d_in[4];  // (M,N,L)
    const float* mscale = (const float*)d_in[5];  // (M,N,L)
    const float* target = (const float*)d_in[6];  // (N,2)
    const float* alpha  = (const float*)d_in[7];
    const float* beta   = (const float*)d_in[8];
    float* out = (float*)d_out;
    float* ws  = (float*)d_ws;

    k1_prep<<<K1_TBL + K1_KL, THREADS, 0, stream>>>(
        jlh, mlh, (const float4*)mloc, (const float4*)mscale, target, ws);
    k2_rank<<<K2_RNK + K2_KL, THREADS, 0, stream>>>(
        (const float4*)mloc, (const float4*)mscale, ws);
    k3_scan<<<K3_SCN + K3_KL, THREADS, 0, stream>>>(
        (const float4*)jloc, (const float4*)jscale, ws);
    k4_final<<<1, 1024, 0, stream>>>(jlh, mlh, target, alpha, beta, ws, out);
}

// Round 6
// 168.011 us; speedup vs baseline: 1.0183x; 1.0183x over previous
//
#include <hip/hip_runtime.h>

#define N 8192
#define M 4
#define L 256

// ws layout (float offsets)
#define WS_SE   0              // [5][N] rank-scattered exp(hazard) — bijective plain stores
#define WS_RANK (5 * N)        // [N]    int ranks (strict-less count)
#define WS_KM   (6 * N)        // [0,1024) modality KL partials, [1024,2048) joint

#define RNK 256                // rank blocks, 32 elements each
#define KLB 1024               // KL streaming blocks
#define GRID_A (RNK + KLB)     // 1280 = exactly 5 blocks/CU at 32 KB LDS — no tail

__device__ __forceinline__ float waveSum(float v) {
#pragma unroll
    for (int off = 32; off > 0; off >>= 1) v += __shfl_down(v, off, 64);
    return v;
}

__device__ __forceinline__ float kl4(float4 l, float4 s) {
    float k;
    k  = 0.5f * (s.x * s.x + l.x * l.x) - __logf(s.x) - 0.5f;
    k += 0.5f * (s.y * s.y + l.y * l.y) - __logf(s.y) - 0.5f;
    k += 0.5f * (s.z * s.z + l.z * l.z) - __logf(s.z) - 0.5f;
    k += 0.5f * (s.w * s.w + l.w * l.w) - __logf(s.w) - 0.5f;
    return k;
}

// ---- kernel A: rank+scatter (256 blocks) ∥ ALL KL streaming (1024 blocks) ----
__global__ __launch_bounds__(256) void kernelA(
    const float* __restrict__ jlh, const float* __restrict__ mlh,
    const float4* __restrict__ jloc4, const float4* __restrict__ jscale4,
    const float4* __restrict__ mloc4, const float4* __restrict__ mscale4,
    const float* __restrict__ target, float* __restrict__ ws)
{
    __shared__ float tc[N];          // 32 KB: rank blocks = compacted times; KL blocks = scratch
    const int tid = threadIdx.x, bid = blockIdx.x;

    if (bid % 5 == 0) {
        // ================= rank + scatter =================
        const int rb = bid / 5;                       // 0..255
        const float4* __restrict__ tg4 = (const float4*)target;
#pragma unroll
        for (int it = 0; it < 16; ++it) {             // compact target -> LDS times
            const int q = it * 256 + tid;             // f4 idx [0, 4096)
            const float4 f = tg4[q];                  // (t2q, e2q, t2q+1, e2q+1)
            tc[2 * q]     = f.x;
            tc[2 * q + 1] = f.z;
        }
        __syncthreads();

        const int e   = rb * 32 + (tid >> 3);         // 8 threads per element
        const int sub = tid & 7;
        const float ti = tc[e];
        const float4* __restrict__ tc4 = (const float4*)tc;
        int rlt = 0, eqlo = 0;
#pragma unroll 8
        for (int k = 0; k < 256; ++k) {
            const float4 t4 = tc4[sub + 8 * k];
            const int j0 = (sub + 8 * k) * 4;
            rlt += (t4.x < ti) ? 1 : 0;
            rlt += (t4.y < ti) ? 1 : 0;
            rlt += (t4.z < ti) ? 1 : 0;
            rlt += (t4.w < ti) ? 1 : 0;
            eqlo += (t4.x == ti && j0     < e) ? 1 : 0;
            eqlo += (t4.y == ti && j0 + 1 < e) ? 1 : 0;
            eqlo += (t4.z == ti && j0 + 2 < e) ? 1 : 0;
            eqlo += (t4.w == ti && j0 + 3 < e) ? 1 : 0;
        }
        // butterfly over the 8-lane group: all lanes end with the group sums
        rlt  += __shfl_xor(rlt, 1, 64);  rlt  += __shfl_xor(rlt, 2, 64);  rlt  += __shfl_xor(rlt, 4, 64);
        eqlo += __shfl_xor(eqlo, 1, 64); eqlo += __shfl_xor(eqlo, 2, 64); eqlo += __shfl_xor(eqlo, 4, 64);
        const int slot = rlt + eqlo;    // stable rank: bijection 0..N-1 even with ties
        if (sub == 7) ((int*)ws)[WS_RANK + e] = rlt;
        if (sub < 5) {                  // scatter exp(hazard) with plain stores
            const float h = (sub == 0) ? jlh[e] : mlh[(sub - 1) * N + e];
            ws[WS_SE + sub * N + slot] = __expf(h);
        }
    } else {
        // ================= KL streaming (all 80 MB) =================
        const int kb = bid - bid / 5 - 1;             // 0..1023
        float km = 0.f, kj = 0.f;
#pragma unroll
        for (int it = 0; it < 8; ++it) {              // modality: 2048 f4-pairs/block
            const int idx = kb * 2048 + it * 256 + tid;
            km += kl4(mloc4[idx], mscale4[idx]);
        }
#pragma unroll
        for (int it = 0; it < 2; ++it) {              // joint: 512 f4-pairs/block
            const int idx = kb * 512 + it * 256 + tid;
            kj += kl4(jloc4[idx], jscale4[idx]);
        }
        km = waveSum(km);
        kj = waveSum(kj);
        const int lane = tid & 63, w = tid >> 6;
        if (lane == 0) { tc[w] = km; tc[4 + w] = kj; }
        __syncthreads();
        if (tid == 0) ws[WS_KM + kb]        = tc[0] + tc[1] + tc[2] + tc[3];
        if (tid == 1) ws[WS_KM + 1024 + kb] = tc[4] + tc[5] + tc[6] + tc[7];
    }
}

// ---- kernel C: suffix-scan (in LDS) + gather + epilogue + combine ----
__global__ __launch_bounds__(1024) void kernelC(
    const float* __restrict__ jlh, const float* __restrict__ mlh,
    const float* __restrict__ target, const float* __restrict__ alpha_p,
    const float* __restrict__ beta_p, float* __restrict__ ws,
    float* __restrict__ out)
{
    __shared__ float suf[N];         // 32 KB suffix table for the current stream
    __shared__ float wt[16];
    __shared__ float red[16][8];

    const int tid = threadIdx.x;
    const int lane = tid & 63, w = tid >> 6;

    // per-thread metadata: 8 contiguous elements
    int   rk[8];
    float ev[8];
#pragma unroll
    for (int k = 0; k < 8; ++k) {
        const int i = tid * 8 + k;
        rk[k] = ((const int*)ws)[WS_RANK + i];
        ev[k] = target[2 * i + 1];
    }
    float evs = 0.f;
#pragma unroll
    for (int k = 0; k < 8; ++k) evs += ev[k];

    float c[5];
#pragma unroll
    for (int s = 0; s < 5; ++s) c[s] = 0.f;

    for (int s = 0; s < 5; ++s) {
        // load this stream's sortedE slice, local inclusive suffix over 8 elems
        const float4* __restrict__ src4 = (const float4*)(ws + WS_SE + s * N);
        const float4 a = src4[tid * 2], b = src4[tid * 2 + 1];
        float v[8];
        v[0] = a.x; v[1] = a.y; v[2] = a.z; v[3] = a.w;
        v[4] = b.x; v[5] = b.y; v[6] = b.z; v[7] = b.w;
#pragma unroll
        for (int k = 6; k >= 0; --k) v[k] += v[k + 1];
        const float T = v[0];
        // wave-level inclusive suffix of per-thread totals
        float x = T;
#pragma unroll
        for (int off = 1; off < 64; off <<= 1) {
            const float y = __shfl_down(x, off, 64);
            if (lane + off < 64) x += y;
        }
        __syncthreads();                 // all gathers of previous stream done
        if (lane == 0) wt[w] = x;        // wave totals
        __syncthreads();
        float offw = 0.f;
        for (int ww = w + 1; ww < 16; ++ww) offw += wt[ww];
        const float excl = offw + (x - T);   // strictly-later threads
#pragma unroll
        for (int k = 0; k < 8; ++k) suf[tid * 8 + k] = excl + v[k];
        __syncthreads();

        // gather + cox partial for this stream
        float cs = 0.f;
#pragma unroll
        for (int k = 0; k < 8; ++k) {
            const int i = tid * 8 + k;
            const float h = (s == 0) ? jlh[i] : mlh[(s - 1) * N + i];
            cs += ev[k] * (h - __logf(suf[rk[k]]));
        }
        c[s] = cs;
    }

    // KL partials (2048 floats, one each for tid<1024)
    const float km = ws[WS_KM + tid];
    const float kj = ws[WS_KM + 1024 + tid];

    float vals[8] = {c[0], c[1], c[2], c[3], c[4], evs, km, kj};
#pragma unroll
    for (int q = 0; q < 8; ++q) {
        vals[q] = waveSum(vals[q]);
        if (lane == 0) red[w][q] = vals[q];
    }
    __syncthreads();
    if (tid == 0) {
        float t[8];
#pragma unroll
        for (int q = 0; q < 8; ++q) {
            float xx = 0.f;
            for (int ww = 0; ww < 16; ++ww) xx += red[ww][q];
            t[q] = xx;
        }
        const float EV = t[5];
        const float alpha = alpha_p[0], beta = beta_p[0];
        const float cox_j = -t[0] / EV;
        const float cox_m = -(t[1] + t[2] + t[3] + t[4]) / EV;
        out[0] = cox_j + beta * (t[7] / (float)N) + alpha * (cox_m + beta * (t[6] / (float)N));
    }
}

extern "C" void kernel_launch(void* const* d_in, const int* in_sizes, int n_in,
                              void* d_out, int out_size, void* d_ws, size_t ws_size,
                              hipStream_t stream) {
    const float* jlh    = (const float*)d_in[0];  // (N,)
    const float* mlh    = (const float*)d_in[1];  // (M,N)
    const float* jloc   = (const float*)d_in[2];  // (N,L)
    const float* jscale = (const float*)d_in[3];  // (N,L)
    const float* mloc   = (const float*)d_in[4];  // (M,N,L)
    const float* mscale = (const float*)d_in[5];  // (M,N,L)
    const float* target = (const float*)d_in[6];  // (N,2)
    const float* alpha  = (const float*)d_in[7];
    const float* beta   = (const float*)d_in[8];
    float* out = (float*)d_out;
    float* ws  = (float*)d_ws;

    kernelA<<<GRID_A, 256, 0, stream>>>(
        jlh, mlh, (const float4*)jloc, (const float4*)jscale,
        (const float4*)mloc, (const float4*)mscale, target, ws);
    kernelC<<<1, 1024, 0, stream>>>(jlh, mlh, target, alpha, beta, ws, out);
}